// Round 2
// baseline (482.527 us; speedup 1.0000x reference)
//
#include <hip/hip_runtime.h>
#include <hip/hip_cooperative_groups.h>

namespace cg = cooperative_groups;

// Problem constants (reference: T=4096, N_ENVS=2048, fp32)
#define TT    4096
#define NENV  2048
#define L     64              // timesteps per chunk (register-resident deltas)
#define NCH   (TT / L)        // 64 chunks
#define CGRP  512             // columns per block (2 per thread)
#define NCGRP (NENV / CGRP)   // 4 column groups
#define NBLK  (NCH * NCGRP)   // 256 blocks -> 1 block/CU needed, 2/CU capacity

__global__ __launch_bounds__(256, 2) void gae_scan_kernel(
    const float* __restrict__ rewards,
    const float* __restrict__ values,
    const float* __restrict__ next_values,
    const int*   __restrict__ next_dones,
    float* __restrict__ adv_out,   // d_out[0 .. T*N)
    float* __restrict__ ret_out,   // d_out[T*N .. 2*T*N)
    float* __restrict__ wsA,       // [NCH * NENV]
    float* __restrict__ wsB)       // [NCH * NENV]
{
    const float GAMMA = 0.99f;
    const float GL    = 0.99f * 0.95f; // gamma * lambda (fp32, matches ref)

    const int chunk = blockIdx.x / NCGRP;          // 0..63
    const int cgrp  = blockIdx.x % NCGRP;          // 0..3
    const int col0  = cgrp * CGRP + threadIdx.x;   // first owned column
    const int col1  = col0 + 256;                  // second owned column
    const int t0    = chunk * L;

    float d0[L], d1[L];                 // deltas for the two columns
    unsigned long long m0 = 0ull, m1 = 0ull; // not_done bitmasks

    // ---- Phase 1: stream inputs once, build per-column chunk affine (A,B) ----
    // g_{t0} = B + A * g_{t0+L}
    float A0 = 1.0f, B0 = 0.0f, A1 = 1.0f, B1 = 0.0f;
#pragma unroll
    for (int i = L - 1; i >= 0; --i) {
        const int row = (t0 + i) * NENV;
        {
            const int idx = row + col0;
            const float r  = rewards[idx];
            const float vv = values[idx];
            const float nv = next_values[idx];
            const int   dn = next_dones[idx];
            const float nd = dn ? 0.0f : 1.0f;
            m0 |= (unsigned long long)(dn == 0) << i;
            const float di = r + GAMMA * nv * nd - vv;
            d0[i] = di;
            const float c = GL * nd;
            B0 = di + c * B0;
            A0 = c * A0;
        }
        {
            const int idx = row + col1;
            const float r  = rewards[idx];
            const float vv = values[idx];
            const float nv = next_values[idx];
            const int   dn = next_dones[idx];
            const float nd = dn ? 0.0f : 1.0f;
            m1 |= (unsigned long long)(dn == 0) << i;
            const float di = r + GAMMA * nv * nd - vv;
            d1[i] = di;
            const float c = GL * nd;
            B1 = di + c * B1;
            A1 = c * A1;
        }
    }
    wsA[chunk * NENV + col0] = A0;
    wsB[chunk * NENV + col0] = B0;
    wsA[chunk * NENV + col1] = A1;
    wsB[chunk * NENV + col1] = B1;

    cg::this_grid().sync();

    // ---- Phase 2: suffix-compose later chunks (L2-resident ws) ----
    float g0 = 0.0f, g1 = 0.0f;
    for (int j = NCH - 1; j > chunk; --j) {
        g0 = wsB[j * NENV + col0] + wsA[j * NENV + col0] * g0;
        g1 = wsB[j * NENV + col1] + wsA[j * NENV + col1] * g1;
    }

    // ---- Phase 3: replay recurrence from registers, write adv & returns ----
#pragma unroll
    for (int i = L - 1; i >= 0; --i) {
        const int row = (t0 + i) * NENV;
        const float c0 = ((m0 >> i) & 1ull) ? GL : 0.0f;
        const float c1 = ((m1 >> i) & 1ull) ? GL : 0.0f;
        g0 = d0[i] + c0 * g0;
        g1 = d1[i] + c1 * g1;
        const int i0 = row + col0;
        const int i1 = row + col1;
        adv_out[i0] = g0;
        adv_out[i1] = g1;
        ret_out[i0] = g0 + values[i0];
        ret_out[i1] = g1 + values[i1];
    }
}

extern "C" void kernel_launch(void* const* d_in, const int* in_sizes, int n_in,
                              void* d_out, int out_size, void* d_ws, size_t ws_size,
                              hipStream_t stream) {
    const float* rewards     = (const float*)d_in[0];
    const float* values      = (const float*)d_in[1];
    const float* next_values = (const float*)d_in[2];
    const int*   next_dones  = (const int*)d_in[3];

    float* adv_out = (float*)d_out;
    float* ret_out = adv_out + (size_t)TT * NENV;

    float* wsA = (float*)d_ws;                 // NCH*NENV floats = 512 KiB
    float* wsB = wsA + (size_t)NCH * NENV;     // another 512 KiB

    void* args[] = {
        (void*)&rewards, (void*)&values, (void*)&next_values, (void*)&next_dones,
        (void*)&adv_out, (void*)&ret_out, (void*)&wsA, (void*)&wsB
    };

    dim3 grid(NBLK);
    dim3 block(256);
    hipLaunchCooperativeKernel((const void*)gae_scan_kernel, grid, block,
                               args, 0, stream);
}

// Round 3
// 206.046 us; speedup vs baseline: 2.3418x; 2.3418x over previous
//
#include <hip/hip_runtime.h>
#include <hip/hip_cooperative_groups.h>

namespace cg = cooperative_groups;

// Problem constants (reference: T=4096, N_ENVS=2048, fp32)
#define TT    4096
#define NENV  2048
#define L     32              // timesteps per chunk (register-resident deltas+values)
#define NCH   (TT / L)        // 128 chunks
#define NCGRP (NENV / 256)    // 8 column groups (1 column per thread, 256 thr/blk)
#define NBLK  (NCH * NCGRP)   // 1024 blocks = 4 blocks/CU on 256 CUs

#define GAMMA 0.99f
#define GL    (0.99f * 0.95f)

// ---------------- Cooperative single-kernel path ----------------
// __launch_bounds__(256,4): min 4 waves/EU -> VGPR cap 128 -> cooperative
// capacity >= 4 blocks/CU = 1024 blocks. d[32]+v[32]+overhead ~ 84 VGPRs.
__global__ __launch_bounds__(256, 4) void gae_coop(
    const float* __restrict__ rewards,
    const float* __restrict__ values,
    const float* __restrict__ next_values,
    const int*   __restrict__ next_dones,
    float* __restrict__ adv_out,
    float* __restrict__ ret_out,
    float* __restrict__ wsA,
    float* __restrict__ wsB)
{
    const int chunk = blockIdx.x / NCGRP;           // 0..127
    const int cgrp  = blockIdx.x % NCGRP;           // 0..7
    const int col   = cgrp * 256 + threadIdx.x;
    const int t0    = chunk * L;

    float d[L];                 // deltas
    float v[L];                 // values (for returns)
    unsigned int mask = 0u;     // bit i => not_done at t0+i

    // Phase 1: stream inputs once; per-chunk affine g_{t0} = B + A*g_{t0+L}
    float A = 1.0f, B = 0.0f;
#pragma unroll
    for (int i = L - 1; i >= 0; --i) {
        const int idx = (t0 + i) * NENV + col;      // coalesced
        const float r  = rewards[idx];
        const float vv = values[idx];
        const float nv = next_values[idx];
        const int   dn = next_dones[idx];
        const float nd = dn ? 0.0f : 1.0f;
        mask |= (unsigned int)(dn == 0) << i;
        const float di = r + GAMMA * nv * nd - vv;
        d[i] = di;
        v[i] = vv;
        const float c = GL * nd;
        B = di + c * B;
        A = c * A;
    }
    wsA[chunk * NENV + col] = A;
    wsB[chunk * NENV + col] = B;

    cg::this_grid().sync();

    // Phase 2: suffix-compose later chunks (ws is ~2 MiB, cache-resident)
    float g = 0.0f;
    for (int j = NCH - 1; j > chunk; --j) {
        g = wsB[j * NENV + col] + wsA[j * NENV + col] * g;
    }

    // Phase 3: replay from registers, write adv & returns
#pragma unroll
    for (int i = L - 1; i >= 0; --i) {
        const float c = ((mask >> i) & 1u) ? GL : 0.0f;
        g = d[i] + c * g;
        const int idx = (t0 + i) * NENV + col;
        adv_out[idx] = g;
        ret_out[idx] = g + v[i];
    }
}

// ---------------- Non-cooperative 3-kernel fallback ----------------
__global__ __launch_bounds__(256) void gae_k1_chunkAB(
    const float* __restrict__ rewards,
    const float* __restrict__ values,
    const float* __restrict__ next_values,
    const int*   __restrict__ next_dones,
    float* __restrict__ wsA,
    float* __restrict__ wsB)
{
    const int chunk = blockIdx.x / NCGRP;
    const int cgrp  = blockIdx.x % NCGRP;
    const int col   = cgrp * 256 + threadIdx.x;
    const int t0    = chunk * L;

    float A = 1.0f, B = 0.0f;
#pragma unroll
    for (int i = L - 1; i >= 0; --i) {
        const int idx = (t0 + i) * NENV + col;
        const float nd = next_dones[idx] ? 0.0f : 1.0f;
        const float di = rewards[idx] + GAMMA * next_values[idx] * nd - values[idx];
        const float c  = GL * nd;
        B = di + c * B;
        A = c * A;
    }
    wsA[chunk * NENV + col] = A;
    wsB[chunk * NENV + col] = B;
}

__global__ __launch_bounds__(256) void gae_k2_scan(
    const float* __restrict__ wsA,
    const float* __restrict__ wsB,
    float* __restrict__ gIn)      // incoming g for each chunk
{
    const int col = blockIdx.x * 256 + threadIdx.x;   // 2048 columns, 8 blocks
    float g = 0.0f;
    for (int j = NCH - 1; j >= 0; --j) {
        gIn[j * NENV + col] = g;
        g = wsB[j * NENV + col] + wsA[j * NENV + col] * g;
    }
}

__global__ __launch_bounds__(256) void gae_k3_replay(
    const float* __restrict__ rewards,
    const float* __restrict__ values,
    const float* __restrict__ next_values,
    const int*   __restrict__ next_dones,
    const float* __restrict__ gIn,
    float* __restrict__ adv_out,
    float* __restrict__ ret_out)
{
    const int chunk = blockIdx.x / NCGRP;
    const int cgrp  = blockIdx.x % NCGRP;
    const int col   = cgrp * 256 + threadIdx.x;
    const int t0    = chunk * L;

    float g = gIn[chunk * NENV + col];
#pragma unroll
    for (int i = L - 1; i >= 0; --i) {
        const int idx = (t0 + i) * NENV + col;
        const float vv = values[idx];
        const float nd = next_dones[idx] ? 0.0f : 1.0f;
        const float di = rewards[idx] + GAMMA * next_values[idx] * nd - vv;
        g = di + GL * nd * g;
        adv_out[idx] = g;
        ret_out[idx] = g + vv;
    }
}

extern "C" void kernel_launch(void* const* d_in, const int* in_sizes, int n_in,
                              void* d_out, int out_size, void* d_ws, size_t ws_size,
                              hipStream_t stream) {
    const float* rewards     = (const float*)d_in[0];
    const float* values      = (const float*)d_in[1];
    const float* next_values = (const float*)d_in[2];
    const int*   next_dones  = (const int*)d_in[3];

    float* adv_out = (float*)d_out;
    float* ret_out = adv_out + (size_t)TT * NENV;

    float* wsA = (float*)d_ws;                      // 1 MiB
    float* wsB = wsA + (size_t)NCH * NENV;          // 1 MiB
    float* gIn = wsB + (size_t)NCH * NENV;          // 1 MiB (fallback only)

    // Host-side capacity check (pure query — graph-capture safe).
    int blocksPerCU = 0;
    (void)hipOccupancyMaxActiveBlocksPerMultiprocessor(
        &blocksPerCU, (const void*)gae_coop, 256, 0);
    const bool coop_ok = (blocksPerCU * 256 >= NBLK);   // 256 CUs on gfx950

    bool launched = false;
    if (coop_ok) {
        void* args[] = {
            (void*)&rewards, (void*)&values, (void*)&next_values, (void*)&next_dones,
            (void*)&adv_out, (void*)&ret_out, (void*)&wsA, (void*)&wsB
        };
        hipError_t e = hipLaunchCooperativeKernel((const void*)gae_coop,
                                                  dim3(NBLK), dim3(256),
                                                  args, 0, stream);
        launched = (e == hipSuccess);
    }
    if (!launched) {
        gae_k1_chunkAB<<<NBLK, 256, 0, stream>>>(rewards, values, next_values,
                                                 next_dones, wsA, wsB);
        gae_k2_scan<<<NENV / 256, 256, 0, stream>>>(wsA, wsB, gIn);
        gae_k3_replay<<<NBLK, 256, 0, stream>>>(rewards, values, next_values,
                                                next_dones, gIn, adv_out, ret_out);
    }
}